// Round 9
// baseline (230.395 us; speedup 1.0000x reference)
//
#include <hip/hip_runtime.h>
#include <math.h>

typedef _Float16 half8_t  __attribute__((ext_vector_type(8)));
typedef _Float16 half4_t  __attribute__((ext_vector_type(4)));
typedef float    floatx16 __attribute__((ext_vector_type(16)));

#define BS   16
#define LL   2048
#define DIMC 512
#define NG   2
#define VD   256
#define NC   320
#define NELEM ((double)(VD*LL))   // 524288 per (b,g)

// global -> LDS direct DMA, 16 B per lane. gsrc per-lane, ldst wave-uniform.
#define GLL(gsrc, ldst) __builtin_amdgcn_global_load_lds( \
    (const __attribute__((address_space(1))) unsigned int*)(gsrc), \
    (__attribute__((address_space(3))) unsigned int*)(ldst), 16, 0, 0)

#define MFMA32 __builtin_amdgcn_mfma_f32_32x32x16_f16

// ---------------------------------------------------------------------------
// k_prep: VERBATIM the passing kernel. Chunk-image f16 hi/lo splits of 16*W
// and 64*E, coalesced. Rows of 72 halves = 144 B: hi[32] lo[32] pad[8].
//   Wimg[g][chunk 8][row 256][72]      Eimg[chunk 8][code 320][72]
// Blocks 0..63: W. 64..103: E. 104..105: e2f. Pow2 scales are exact.
// ---------------------------------------------------------------------------
__global__ void k_prep(const float* __restrict__ W, const float* __restrict__ emb,
                       _Float16* __restrict__ Wimg, _Float16* __restrict__ Eimg,
                       float* __restrict__ e2f)
{
  const int blk = blockIdx.x, t = threadIdx.x;
  if (blk < 64) {
    int base = (blk * 256 + t) * 8;        // flat (g,o,v), 8 contiguous
    int k = base & 255, c = k >> 5, kk = k & 31;   // kk in {0,8,16,24}
    int row = (base >> 8) & 255, g = base >> 16;
    float4 v0 = *(const float4*)(W + base);
    float4 v1 = *(const float4*)(W + base + 4);
    float vv[8] = {v0.x, v0.y, v0.z, v0.w, v1.x, v1.y, v1.z, v1.w};
    half8_t hh, ll;
    #pragma unroll
    for (int i = 0; i < 8; ++i) {
      float s = vv[i] * 16.0f;
      _Float16 h = (_Float16)s;
      hh[i] = h; ll[i] = (_Float16)(s - (float)h);
    }
    size_t rb = ((size_t)(g * 8 + c) * 256 + row) * 72;
    *(half8_t*)&Wimg[rb + kk]      = hh;
    *(half8_t*)&Wimg[rb + 32 + kk] = ll;
  } else if (blk < 104) {
    int base = ((blk - 64) * 256 + t) * 8; // flat (code,v)
    int k = base & 255, c = k >> 5, kk = k & 31;
    int code = base >> 8;
    float4 v0 = *(const float4*)(emb + base);
    float4 v1 = *(const float4*)(emb + base + 4);
    float vv[8] = {v0.x, v0.y, v0.z, v0.w, v1.x, v1.y, v1.z, v1.w};
    half8_t hh, ll;
    #pragma unroll
    for (int i = 0; i < 8; ++i) {
      float s = vv[i] * 64.0f;
      _Float16 h = (_Float16)s;
      hh[i] = h; ll[i] = (_Float16)(s - (float)h);
    }
    size_t rb = ((size_t)c * 320 + code) * 72;
    *(half8_t*)&Eimg[rb + kk]      = hh;
    *(half8_t*)&Eimg[rb + 32 + kk] = ll;
  } else {
    int code = (blk - 104) * 256 + t;
    if (code < NC) {
      const float* er = emb + (size_t)code * VD;
      double s[4] = {0.0, 0.0, 0.0, 0.0};
      for (int v = 0; v < VD; v += 16)
        #pragma unroll
        for (int u = 0; u < 4; ++u) {
          float4 e4 = *(const float4*)(er + v + u * 4);
          s[u] += (double)e4.x * e4.x + (double)e4.y * e4.y
                + (double)e4.z * e4.z + (double)e4.w * e4.w;
        }
      e2f[code] = (float)(64.0 * (s[0] + s[1] + s[2] + s[3]));
    }
  }
}

// ---------------------------------------------------------------------------
// k_proj: 2-phase double-buffered pipeline, 512 threads (8 waves), 1 blk/CU.
// Per chunk: barrier -> issue GLL W[c+1] + X[c+1] reg-loads -> MFMA[c] ->
// split/write X[c+1]. Single barrier/chunk; GLL drain covered by MFMA phase.
// Wave partition: (w&1)=pos-half(64), (w>>1)=out-quarter(64). Each acc's
// MFMA chain (c asc, ks asc, hh/hl/lh) identical to the passing R7 kernel ->
// ze bit-identical. Stats wave-grouping differs only at f64 2^-52 rounding
// (same scale as baseline's atomic-order wobble).
// ---------------------------------------------------------------------------
__global__ __launch_bounds__(512, 1) void k_proj(
    const float* __restrict__ x, const _Float16* __restrict__ Wimg,
    float* __restrict__ ze, double* __restrict__ stats)
{
  __shared__ _Float16 Ah[2][128][72];    // 36864 B
  __shared__ _Float16 Bh[2][256 * 72];   // 73728 B -> 110.6 KB total

  const int blk = blockIdx.x;
  const int g  = blk & 1;
  const int m0 = (blk >> 1) * 128;     // flat position b*2048+l
  const int b  = m0 >> 11;
  const int t  = threadIdx.x;
  const int lane = t & 63, w = t >> 6;
  const int col  = lane & 31, hq = lane >> 5;
  const int pw = (w & 1) * 64, ow = (w >> 1) * 64;
  const int rw = t >> 3, kq = t & 7;   // staging: row-base, fixed k-quad

  const char* wbase = (const char*)(Wimg + (size_t)g * 8 * 256 * 72);
  const float* xrow = x + (size_t)m0 * DIMC + g * VD + kq * 4;

  floatx16 acc[2][2];
  #pragma unroll
  for (int i = 0; i < 2; ++i)
    #pragma unroll
    for (int j = 0; j < 2; ++j)
      #pragma unroll
      for (int e = 0; e < 16; ++e) acc[i][j][e] = 0.f;

  // prologue: stage chunk 0 into buffer 0
  for (int i = w; i < 36; i += 8) {
    int off = i * 1024 + lane * 16;
    GLL(wbase + off, (char*)Bh[0] + off);
  }
  #pragma unroll
  for (int i = 0; i < 2; ++i) {
    int row = i * 64 + rw;
    float4 v = *(const float4*)(xrow + (size_t)row * DIMC);
    half4_t hh, ll;
    { _Float16 h = (_Float16)v.x; hh[0] = h; ll[0] = (_Float16)(v.x - (float)h); }
    { _Float16 h = (_Float16)v.y; hh[1] = h; ll[1] = (_Float16)(v.y - (float)h); }
    { _Float16 h = (_Float16)v.z; hh[2] = h; ll[2] = (_Float16)(v.z - (float)h); }
    { _Float16 h = (_Float16)v.w; hh[3] = h; ll[3] = (_Float16)(v.w - (float)h); }
    *(half4_t*)&Ah[0][row][kq * 4]      = hh;
    *(half4_t*)&Ah[0][row][32 + kq * 4] = ll;
  }

  for (int c = 0; c < 8; ++c) {
    __syncthreads();                    // drains chunk-c GLL + staging writes
    const int cur = c & 1, nxt = cur ^ 1;
    if (c < 7) {                        // issue next W-image DMA (in flight
      const char* wc = wbase + (size_t)(c + 1) * 256 * 144;   // across MFMA)
      for (int i = w; i < 36; i += 8) {
        int off = i * 1024 + lane * 16;
        GLL(wc + off, (char*)Bh[nxt] + off);
      }
    }
    float4 xv[2];                       // issue next X loads early (T14)
    if (c < 7) {
      #pragma unroll
      for (int i = 0; i < 2; ++i)
        xv[i] = *(const float4*)(xrow + (size_t)(i * 64 + rw) * DIMC + (c + 1) * 32);
    }
    // MFMA phase on current buffers
    #pragma unroll
    for (int ks = 0; ks < 2; ++ks) {
      const int ko = ks * 16 + hq * 8;
      half8_t azh[2], azl[2], bwh[2], bwl[2];
      #pragma unroll
      for (int i = 0; i < 2; ++i) {
        azh[i] = *(const half8_t*)&Ah[cur][pw + i * 32 + col][ko];
        azl[i] = *(const half8_t*)&Ah[cur][pw + i * 32 + col][32 + ko];
        bwh[i] = *(const half8_t*)&Bh[cur][(ow + i * 32 + col) * 72 + ko];
        bwl[i] = *(const half8_t*)&Bh[cur][(ow + i * 32 + col) * 72 + 32 + ko];
      }
      #pragma unroll
      for (int mi = 0; mi < 2; ++mi)
        #pragma unroll
        for (int ni = 0; ni < 2; ++ni) {
          acc[mi][ni] = MFMA32(azh[mi], bwh[ni], acc[mi][ni], 0, 0, 0);
          acc[mi][ni] = MFMA32(azh[mi], bwl[ni], acc[mi][ni], 0, 0, 0);
          acc[mi][ni] = MFMA32(azl[mi], bwh[ni], acc[mi][ni], 0, 0, 0);
        }
    }
    if (c < 7) {                        // write-late: split next X into nxt
      #pragma unroll
      for (int i = 0; i < 2; ++i) {
        int row = i * 64 + rw;
        half4_t hh, ll;
        { _Float16 h = (_Float16)xv[i].x; hh[0] = h; ll[0] = (_Float16)(xv[i].x - (float)h); }
        { _Float16 h = (_Float16)xv[i].y; hh[1] = h; ll[1] = (_Float16)(xv[i].y - (float)h); }
        { _Float16 h = (_Float16)xv[i].z; hh[2] = h; ll[2] = (_Float16)(xv[i].z - (float)h); }
        { _Float16 h = (_Float16)xv[i].w; hh[3] = h; ll[3] = (_Float16)(xv[i].w - (float)h); }
        *(half4_t*)&Ah[nxt][row][kq * 4]      = hh;
        *(half4_t*)&Ah[nxt][row][32 + kq * 4] = ll;
      }
    }
  }

  // epilogue: scale back 1/16 (exact), fp64 stats, stores (values verbatim)
  double s1 = 0.0, s2 = 0.0;
  #pragma unroll
  for (int mi = 0; mi < 2; ++mi)
    #pragma unroll
    for (int ni = 0; ni < 2; ++ni)
      #pragma unroll
      for (int r = 0; r < 16; ++r) {
        float vv = acc[mi][ni][r] * 0.0625f;
        double d = (double)vv; s1 += d; s2 += d * d;
        int ml = pw + mi * 32 + (r & 3) + 8 * (r >> 2) + 4 * hq;
        int nl = ow + ni * 32 + col;
        ze[((size_t)(m0 + ml)) * DIMC + g * VD + nl] = vv;
      }
  #pragma unroll
  for (int off = 32; off > 0; off >>= 1) {
    s1 += __shfl_down(s1, off);
    s2 += __shfl_down(s2, off);
  }
  if (lane == 0) {
    atomicAdd(&stats[(b * NG + g) * 2 + 0], s1);
    atomicAdd(&stats[(b * NG + g) * 2 + 1], s2);
  }
}

// ---------------------------------------------------------------------------
// k_vq: same 2-phase dbuf template. 512 threads: (w&3)=pos-quarter(32),
// (w>>2)=code-half(5 tiles). Per chunk: barrier -> GLL E'[c+1] + ze[c+1]
// reg-loads -> MFMA[c] -> normalize/split-write Z[c+1]. Distances and the
// lexicographic argmin are bit-identical to R7 (same chains, same combine
// order mh0-then-mh1). Epilogue: out rows = emb[idx].
// ---------------------------------------------------------------------------
__global__ __launch_bounds__(512, 1) void k_vq(
    float* __restrict__ zio, const float* __restrict__ emb,
    const _Float16* __restrict__ Eimg,
    const float* __restrict__ gnw, const float* __restrict__ gnb,
    const double* __restrict__ stats, const float* __restrict__ e2f)
{
  __shared__ _Float16 Zs[2][128][72];   // 36864 B
  __shared__ _Float16 Es[2][320 * 72];  // 92160 B
  __shared__ float e2sh[NC];
  __shared__ int   idxs[128];
  __shared__ float cndv[2][128];
  __shared__ int   cndi[2][128];        // -> 132.9 KB total

  const int blk = blockIdx.x;
  const int g  = blk & 1;
  const int m0 = (blk >> 1) * 128;
  const int b  = m0 >> 11;
  const int t  = threadIdx.x;
  const int lane = t & 63, w = t >> 6;
  const int col  = lane & 31, hq = lane >> 5;
  const int ph = (w & 3) * 32;         // pos-quarter rows ph..ph+31
  const int mh = (w >> 2) * 5;         // code tiles mh..mh+4
  const int rw = t >> 3, kq = t & 7;

  // finalize stats inline (uniform per block; identical fp64 math every call)
  const int si = b * NG + g;
  double ss1 = stats[2 * si], ss2 = stats[2 * si + 1];
  double mu = ss1 / NELEM, var = ss2 / NELEM - mu * mu;
  const float mean = (float)mu;
  const float rstd = (float)(1.0 / sqrt(var + 1e-5));

  for (int cc = t; cc < NC; cc += 512) e2sh[cc] = e2f[cc];

  float* zbase = zio + (size_t)m0 * DIMC + g * VD;
  const float* zrow = zbase + kq * 4;
  const float* gw = gnw + g * VD;
  const float* gb = gnb + g * VD;

  floatx16 acc[5];
  #pragma unroll
  for (int i = 0; i < 5; ++i)
    #pragma unroll
    for (int e = 0; e < 16; ++e) acc[i][e] = 0.f;

  // prologue: stage chunk 0 into buffer 0
  for (int i = w; i < 45; i += 8) {
    int off = i * 1024 + lane * 16;
    GLL((const char*)Eimg + off, (char*)Es[0] + off);
  }
  {
    float4 wv = *(const float4*)(gw + kq * 4);
    float4 bv = *(const float4*)(gb + kq * 4);
    #pragma unroll
    for (int i = 0; i < 2; ++i) {
      int row = i * 64 + rw;
      float4 v = *(const float4*)(zrow + (size_t)row * DIMC);
      float zn0 = (v.x - mean) * rstd * wv.x + bv.x;
      float zn1 = (v.y - mean) * rstd * wv.y + bv.y;
      float zn2 = (v.z - mean) * rstd * wv.z + bv.z;
      float zn3 = (v.w - mean) * rstd * wv.w + bv.w;
      half4_t hh, ll;
      { _Float16 h = (_Float16)zn0; hh[0] = h; ll[0] = (_Float16)(zn0 - (float)h); }
      { _Float16 h = (_Float16)zn1; hh[1] = h; ll[1] = (_Float16)(zn1 - (float)h); }
      { _Float16 h = (_Float16)zn2; hh[2] = h; ll[2] = (_Float16)(zn2 - (float)h); }
      { _Float16 h = (_Float16)zn3; hh[3] = h; ll[3] = (_Float16)(zn3 - (float)h); }
      *(half4_t*)&Zs[0][row][kq * 4]      = hh;
      *(half4_t*)&Zs[0][row][32 + kq * 4] = ll;
    }
  }

  for (int c = 0; c < 8; ++c) {
    __syncthreads();                    // drains chunk-c GLL + staging writes
    const int cur = c & 1, nxt = cur ^ 1;
    if (c < 7) {
      const char* ec = (const char*)Eimg + (size_t)(c + 1) * 320 * 144;
      for (int i = w; i < 45; i += 8) {
        int off = i * 1024 + lane * 16;
        GLL(ec + off, (char*)Es[nxt] + off);
      }
    }
    float4 zv[2], wv, bv;               // issue next ze/gn loads early (T14)
    if (c < 7) {
      wv = *(const float4*)(gw + (c + 1) * 32 + kq * 4);
      bv = *(const float4*)(gb + (c + 1) * 32 + kq * 4);
      #pragma unroll
      for (int i = 0; i < 2; ++i)
        zv[i] = *(const float4*)(zrow + (size_t)(i * 64 + rw) * DIMC + (c + 1) * 32);
    }
    // MFMA phase on current buffers
    #pragma unroll
    for (int ks = 0; ks < 2; ++ks) {
      const int ko = ks * 16 + hq * 8;
      half8_t bzh = *(const half8_t*)&Zs[cur][ph + col][ko];
      half8_t bzl = *(const half8_t*)&Zs[cur][ph + col][32 + ko];
      #pragma unroll
      for (int mtl = 0; mtl < 5; ++mtl) {
        const _Float16* erow = &Es[cur][((mh + mtl) * 32 + col) * 72];
        half8_t aeh = *(const half8_t*)&erow[ko];
        half8_t ael = *(const half8_t*)&erow[32 + ko];
        acc[mtl] = MFMA32(aeh, bzh, acc[mtl], 0, 0, 0);
        acc[mtl] = MFMA32(aeh, bzl, acc[mtl], 0, 0, 0);
        acc[mtl] = MFMA32(ael, bzh, acc[mtl], 0, 0, 0);
      }
    }
    if (c < 7) {                        // write-late: normalize+split into nxt
      #pragma unroll
      for (int i = 0; i < 2; ++i) {
        int row = i * 64 + rw;
        float zn0 = (zv[i].x - mean) * rstd * wv.x + bv.x;
        float zn1 = (zv[i].y - mean) * rstd * wv.y + bv.y;
        float zn2 = (zv[i].z - mean) * rstd * wv.z + bv.z;
        float zn3 = (zv[i].w - mean) * rstd * wv.w + bv.w;
        half4_t hh, ll;
        { _Float16 h = (_Float16)zn0; hh[0] = h; ll[0] = (_Float16)(zn0 - (float)h); }
        { _Float16 h = (_Float16)zn1; hh[1] = h; ll[1] = (_Float16)(zn1 - (float)h); }
        { _Float16 h = (_Float16)zn2; hh[2] = h; ll[2] = (_Float16)(zn2 - (float)h); }
        { _Float16 h = (_Float16)zn3; hh[3] = h; ll[3] = (_Float16)(zn3 - (float)h); }
        *(half4_t*)&Zs[nxt][row][kq * 4]      = hh;
        *(half4_t*)&Zs[nxt][row][32 + kq * 4] = ll;
      }
    }
  }

  // argmin: in-lane over 5 tiles x 16 regs (lexicographic (d,code) min),
  // combine hq pair via shfl_xor(32), then mh0-vs-mh1 in fixed order.
  float bvv = 3.4e38f; int bii = 0x7fffffff;
  #pragma unroll
  for (int mtl = 0; mtl < 5; ++mtl)
    #pragma unroll
    for (int r = 0; r < 16; ++r) {
      int code = (mh + mtl) * 32 + (r & 3) + 8 * (r >> 2) + 4 * hq;
      float d = e2sh[code] - 2.0f * acc[mtl][r];
      if (d < bvv || (d == bvv && code < bii)) { bvv = d; bii = code; }
    }
  {
    float ov = __shfl_xor(bvv, 32); int oi = __shfl_xor(bii, 32);
    if (ov < bvv || (ov == bvv && oi < bii)) { bvv = ov; bii = oi; }
  }
  if (hq == 0) {
    cndv[w >> 2][ph + col] = bvv;
    cndi[w >> 2][ph + col] = bii;
  }
  __syncthreads();
  if (t < 128) {
    float v0 = cndv[0][t], v1 = cndv[1][t];
    int   i0 = cndi[0][t], i1 = cndi[1][t];
    idxs[t] = (v1 < v0 || (v1 == v0 && i1 < i0)) ? i1 : i0;
  }
  __syncthreads();

  // epilogue: out rows = emb[idx] (pure gather, no ze re-read)
  #pragma unroll
  for (int it = 0; it < 16; ++it) {
    int idx = it * 512 + t;             // 0..8191
    int row = idx >> 6, q4 = (idx & 63) * 4;
    int id = idxs[row];
    float4 e4 = *(const float4*)(emb + (size_t)id * VD + q4);
    *(float4*)(zbase + (size_t)row * DIMC + q4) = e4;
  }
}

extern "C" void kernel_launch(void* const* d_in, const int* in_sizes, int n_in,
                              void* d_out, int out_size, void* d_ws, size_t ws_size,
                              hipStream_t stream) {
  const float* x   = (const float*)d_in[0];
  const float* W   = (const float*)d_in[1];   // (2,256,256)
  const float* gnw = (const float*)d_in[2];   // (512,)
  const float* gnb = (const float*)d_in[3];   // (512,)
  const float* emb = (const float*)d_in[4];   // (320,1,256)
  float* out = (float*)d_out;

  double*   stats = (double*)d_ws;                       // 512 B
  float*    e2f   = (float*)((char*)d_ws + 512);         // 1280 B
  _Float16* Wimg  = (_Float16*)((char*)d_ws + 2048);     // 589824 B
  _Float16* Eimg  = (_Float16*)((char*)d_ws + 591872);   // 368640 B -> 960512 total

  hipMemsetAsync(d_ws, 0, 512, stream);
  k_prep<<<106, 256, 0, stream>>>(W, emb, Wimg, Eimg, e2f);
  k_proj<<<512, 512, 0, stream>>>(x, Wimg, out, stats);
  k_vq<<<512, 512, 0, stream>>>(out, emb, Eimg, gnw, gnb, stats, e2f);
}

// Round 10
// 197.950 us; speedup vs baseline: 1.1639x; 1.1639x over previous
//
#include <hip/hip_runtime.h>
#include <math.h>

typedef _Float16 half8_t  __attribute__((ext_vector_type(8)));
typedef _Float16 half4_t  __attribute__((ext_vector_type(4)));
typedef float    floatx16 __attribute__((ext_vector_type(16)));

#define BS   16
#define LL   2048
#define DIMC 512
#define NG   2
#define VD   256
#define NC   320
#define NELEM ((double)(VD*LL))   // 524288 per (b,g)

// global -> LDS direct DMA, 16 B per lane. gsrc per-lane, ldst wave-uniform.
#define GLL(gsrc, ldst) __builtin_amdgcn_global_load_lds( \
    (const __attribute__((address_space(1))) unsigned int*)(gsrc), \
    (__attribute__((address_space(3))) unsigned int*)(ldst), 16, 0, 0)

#define MFMA32 __builtin_amdgcn_mfma_f32_32x32x16_f16

// ---------------------------------------------------------------------------
// k_prep: chunk-image f16 hi/lo splits of 16*W and 64*E (pow2 scales exact).
// Rows of 72 halves = 144 B: hi[32] lo[32] pad[8].
//   Wimg[g][chunk 8][row 256][72]
//   Eimg[tile 10][chunk 8][code 32][72]   (tile-major, R4-proven layout)
// Blocks 0..63: W. 64..103: E. 104..105: e2f. Block 105 t in [64,128) also
// zeroes stats (replaces the hipMemsetAsync node; stream order guarantees
// completion before k_proj's atomics).
// ---------------------------------------------------------------------------
__global__ void k_prep(const float* __restrict__ W, const float* __restrict__ emb,
                       _Float16* __restrict__ Wimg, _Float16* __restrict__ Eimg,
                       float* __restrict__ e2f, double* __restrict__ stats)
{
  const int blk = blockIdx.x, t = threadIdx.x;
  if (blk < 64) {
    int base = (blk * 256 + t) * 8;        // flat (g,o,v), 8 contiguous
    int k = base & 255, c = k >> 5, kk = k & 31;   // kk in {0,8,16,24}
    int row = (base >> 8) & 255, g = base >> 16;
    float4 v0 = *(const float4*)(W + base);
    float4 v1 = *(const float4*)(W + base + 4);
    float vv[8] = {v0.x, v0.y, v0.z, v0.w, v1.x, v1.y, v1.z, v1.w};
    half8_t hh, ll;
    #pragma unroll
    for (int i = 0; i < 8; ++i) {
      float s = vv[i] * 16.0f;
      _Float16 h = (_Float16)s;
      hh[i] = h; ll[i] = (_Float16)(s - (float)h);
    }
    size_t rb = ((size_t)(g * 8 + c) * 256 + row) * 72;
    *(half8_t*)&Wimg[rb + kk]      = hh;
    *(half8_t*)&Wimg[rb + 32 + kk] = ll;
  } else if (blk < 104) {
    int base = ((blk - 64) * 256 + t) * 8; // flat (code,v)
    int k = base & 255, c = k >> 5, kk = k & 31;
    int code = base >> 8;
    int mt = code >> 5, cl = code & 31;
    float4 v0 = *(const float4*)(emb + base);
    float4 v1 = *(const float4*)(emb + base + 4);
    float vv[8] = {v0.x, v0.y, v0.z, v0.w, v1.x, v1.y, v1.z, v1.w};
    half8_t hh, ll;
    #pragma unroll
    for (int i = 0; i < 8; ++i) {
      float s = vv[i] * 64.0f;
      _Float16 h = (_Float16)s;
      hh[i] = h; ll[i] = (_Float16)(s - (float)h);
    }
    size_t rb = ((size_t)((mt * 8 + c) * 32 + cl)) * 72;
    *(half8_t*)&Eimg[rb + kk]      = hh;
    *(half8_t*)&Eimg[rb + 32 + kk] = ll;
  } else {
    int code = (blk - 104) * 256 + t;
    if (code < NC) {
      const float* er = emb + (size_t)code * VD;
      double s[4] = {0.0, 0.0, 0.0, 0.0};
      for (int v = 0; v < VD; v += 16)
        #pragma unroll
        for (int u = 0; u < 4; ++u) {
          float4 e4 = *(const float4*)(er + v + u * 4);
          s[u] += (double)e4.x * e4.x + (double)e4.y * e4.y
                + (double)e4.z * e4.z + (double)e4.w * e4.w;
        }
      e2f[code] = (float)(64.0 * (s[0] + s[1] + s[2] + s[3]));
    }
    if (blk == 105 && t >= 64 && t < 128) stats[t - 64] = 0.0;
  }
}

// ---------------------------------------------------------------------------
// k_proj: R7-verbatim structure (256t, 2 blk/CU, 55.3 KB LDS) + x-prefetch
// hoist: chunk c+1's x loads issue AFTER the pre-MFMA barrier (drain at the
// post-MFMA barrier, covered by the MFMA phase) and are consumed by the next
// split — removing the ~900-cyc HBM exposure from the staging phase.
// All arithmetic chains identical to the passing kernel -> ze bit-identical.
// ---------------------------------------------------------------------------
__global__ __launch_bounds__(256, 2) void k_proj(
    const float* __restrict__ x, const _Float16* __restrict__ Wimg,
    float* __restrict__ ze, double* __restrict__ stats)
{
  __shared__ _Float16 Ah[128][72];
  __shared__ _Float16 Bh[256 * 72];

  const int blk = blockIdx.x;
  const int g  = blk & 1;
  const int m0 = (blk >> 1) * 128;     // flat position b*2048+l
  const int b  = m0 >> 11;
  const int t  = threadIdx.x;
  const int lane = t & 63, w = t >> 6;
  const int col  = lane & 31, hq = lane >> 5;
  const int mw = (w & 1) * 64, nw = (w >> 1) * 128;
  const int rw = t >> 3, kq = t & 7;   // staging coords

  const char* wbase = (const char*)(Wimg + (size_t)g * 8 * 256 * 72);
  const float* xrow = x + (size_t)m0 * DIMC + g * VD + kq * 4;

  floatx16 acc[2][4];
  #pragma unroll
  for (int i = 0; i < 2; ++i)
    #pragma unroll
    for (int j = 0; j < 4; ++j)
      #pragma unroll
      for (int e = 0; e < 16; ++e) acc[i][j][e] = 0.f;

  // prologue: x loads for chunk 0 (one exposed latency)
  float4 xv[4];
  #pragma unroll
  for (int i = 0; i < 4; ++i)
    xv[i] = *(const float4*)(xrow + (size_t)(i * 32 + rw) * DIMC);

  for (int c = 0; c < 8; ++c) {
    // W chunk image via global_load_lds (9 per wave) — covered by split VALU
    {
      const char* wc = wbase + (size_t)c * 256 * 144;
      #pragma unroll
      for (int i = 0; i < 9; ++i) {
        int off = (w * 9 + i) * 1024 + lane * 16;
        GLL(wc + off, (char*)Bh + off);
      }
    }
    // split xv (already arrived) -> Ah
    #pragma unroll
    for (int i = 0; i < 4; ++i) {
      int row = i * 32 + rw;
      half4_t hh, ll;
      { _Float16 h = (_Float16)xv[i].x; hh[0] = h; ll[0] = (_Float16)(xv[i].x - (float)h); }
      { _Float16 h = (_Float16)xv[i].y; hh[1] = h; ll[1] = (_Float16)(xv[i].y - (float)h); }
      { _Float16 h = (_Float16)xv[i].z; hh[2] = h; ll[2] = (_Float16)(xv[i].z - (float)h); }
      { _Float16 h = (_Float16)xv[i].w; hh[3] = h; ll[3] = (_Float16)(xv[i].w - (float)h); }
      *(half4_t*)&Ah[row][kq * 4]      = hh;
      *(half4_t*)&Ah[row][32 + kq * 4] = ll;
    }
    __syncthreads();
    if (c < 7) {                        // hoisted prefetch: drains at the
      #pragma unroll                    // post-MFMA barrier, covered by MFMA
      for (int i = 0; i < 4; ++i)
        xv[i] = *(const float4*)(xrow + (size_t)(i * 32 + rw) * DIMC + (c + 1) * 32);
    }
    #pragma unroll
    for (int ks = 0; ks < 2; ++ks) {
      const int ko = ks * 16 + hq * 8;
      half8_t azh[2], azl[2], bwh[4], bwl[4];
      #pragma unroll
      for (int i = 0; i < 2; ++i) {
        azh[i] = *(const half8_t*)&Ah[mw + i * 32 + col][ko];
        azl[i] = *(const half8_t*)&Ah[mw + i * 32 + col][32 + ko];
      }
      #pragma unroll
      for (int j = 0; j < 4; ++j) {
        bwh[j] = *(const half8_t*)&Bh[(nw + j * 32 + col) * 72 + ko];
        bwl[j] = *(const half8_t*)&Bh[(nw + j * 32 + col) * 72 + 32 + ko];
      }
      #pragma unroll
      for (int mi = 0; mi < 2; ++mi)
        #pragma unroll
        for (int ni = 0; ni < 4; ++ni) {
          acc[mi][ni] = MFMA32(azh[mi], bwh[ni], acc[mi][ni], 0, 0, 0);
          acc[mi][ni] = MFMA32(azh[mi], bwl[ni], acc[mi][ni], 0, 0, 0);
          acc[mi][ni] = MFMA32(azl[mi], bwh[ni], acc[mi][ni], 0, 0, 0);
        }
    }
    __syncthreads();
  }

  // epilogue: scale back 1/16 (exact), fp64 stats, stores (verbatim)
  double s1 = 0.0, s2 = 0.0;
  #pragma unroll
  for (int mi = 0; mi < 2; ++mi)
    #pragma unroll
    for (int ni = 0; ni < 4; ++ni)
      #pragma unroll
      for (int r = 0; r < 16; ++r) {
        float vv = acc[mi][ni][r] * 0.0625f;
        double d = (double)vv; s1 += d; s2 += d * d;
        int ml = mw + mi * 32 + (r & 3) + 8 * (r >> 2) + 4 * hq;
        int nl = nw + ni * 32 + col;
        ze[((size_t)(m0 + ml)) * DIMC + g * VD + nl] = vv;
      }
  #pragma unroll
  for (int off = 32; off > 0; off >>= 1) {
    s1 += __shfl_down(s1, off);
    s2 += __shfl_down(s2, off);
  }
  if (lane == 0) {
    atomicAdd(&stats[(b * NG + g) * 2 + 0], s1);
    atomicAdd(&stats[(b * NG + g) * 2 + 1], s2);
  }
}

// ---------------------------------------------------------------------------
// k_vq: phase-separated (R4-proven numerics), 256t, 2 blk/CU, 75.5 KB LDS.
// Phase Z: 8 ping-pong chunks {issue ze loads -> read prev chunk's B-frags
// into registers -> normalize/split-write} — pure memory, no MFMA islands.
// Phase VQ: 10 code tiles (tile-major Eimg, 36.9 KB, GLL double-buffered
// from L2) x 48 MFMA/wave, Z entirely in registers (zfh/zfl = 128 VGPR).
// Distance rounding path, lexicographic argmin visit order, and the gather
// epilogue are identical to the passing kernel -> bit-identical output.
// LDS aliasing: EsA [0,36864)B overlays Zs0/Zs1 (dead after phase Z);
// EsB [36864,73728)B holds tile 0 (preloaded during phase Z).
// ---------------------------------------------------------------------------
__global__ __launch_bounds__(256, 2) void k_vq(
    float* __restrict__ zio, const float* __restrict__ emb,
    const _Float16* __restrict__ Eimg,
    const float* __restrict__ gnw, const float* __restrict__ gnb,
    const double* __restrict__ stats, const float* __restrict__ e2f)
{
  __shared__ __align__(16) _Float16 smem[36864];  // 73728 B
  __shared__ float e2sh[NC];
  __shared__ int   idxs[128];

  _Float16* const Zs0 = smem;           // [128][72] halves [0,9216)
  _Float16* const Zs1 = smem + 9216;    // [128][72] halves [9216,18432)
  _Float16* const EsA = smem;           // odd tiles  (36864 B, aliases Zs)
  _Float16* const EsB = smem + 18432;   // even tiles (36864 B)

  const int blk = blockIdx.x;
  const int g  = blk & 1;
  const int m0 = (blk >> 1) * 128;
  const int b  = m0 >> 11;
  const int t  = threadIdx.x;
  const int lane = t & 63, w = t >> 6;
  const int col  = lane & 31, hq = lane >> 5;
  const int rw = t >> 3, kq = t & 7;

  // finalize stats inline (uniform per block; identical fp64 math every call)
  const int si = b * NG + g;
  double ss1 = stats[2 * si], ss2 = stats[2 * si + 1];
  double mu = ss1 / NELEM, var = ss2 / NELEM - mu * mu;
  const float mean = (float)mu;
  const float rstd = (float)(1.0 / sqrt(var + 1e-5));

  for (int cc = t; cc < NC; cc += 256) e2sh[cc] = e2f[cc];

  float* zbase = zio + (size_t)m0 * DIMC + g * VD;
  const float* gw = gnw + g * VD;
  const float* gb = gnb + g * VD;

  // ---------------- phase Z: build B-fragments in registers ----------------
  half8_t zfh[8][2], zfl[8][2];

  // tile-0 Eimg GLL into EsB (in flight under phase Z)
  {
    const char* ec = (const char*)Eimg;
    #pragma unroll
    for (int i = 0; i < 9; ++i) {
      int off = (w * 9 + i) * 1024 + lane * 16;
      GLL(ec + off, (char*)EsB + off);
    }
  }
  // stage chunk 0 -> Zs0 (normalize + split, verbatim arithmetic)
  {
    float4 w4 = *(const float4*)(gw + kq * 4);
    float4 b4 = *(const float4*)(gb + kq * 4);
    #pragma unroll
    for (int i = 0; i < 4; ++i) {
      int row = i * 32 + rw;
      float4 v = *(const float4*)(zbase + (size_t)row * DIMC + kq * 4);
      float zn0 = (v.x - mean) * rstd * w4.x + b4.x;
      float zn1 = (v.y - mean) * rstd * w4.y + b4.y;
      float zn2 = (v.z - mean) * rstd * w4.z + b4.z;
      float zn3 = (v.w - mean) * rstd * w4.w + b4.w;
      half4_t hh, ll;
      { _Float16 h = (_Float16)zn0; hh[0] = h; ll[0] = (_Float16)(zn0 - (float)h); }
      { _Float16 h = (_Float16)zn1; hh[1] = h; ll[1] = (_Float16)(zn1 - (float)h); }
      { _Float16 h = (_Float16)zn2; hh[2] = h; ll[2] = (_Float16)(zn2 - (float)h); }
      { _Float16 h = (_Float16)zn3; hh[3] = h; ll[3] = (_Float16)(zn3 - (float)h); }
      *(half4_t*)&Zs0[row * 72 + kq * 4]      = hh;
      *(half4_t*)&Zs0[row * 72 + 32 + kq * 4] = ll;
    }
  }
  #pragma unroll
  for (int c = 1; c < 8; ++c) {
    __syncthreads();                    // Zs[(c-1)&1] ready
    // early-issue chunk-c loads (ze is L3-resident; covered by frag reads)
    float4 zv[4];
    float4 w4 = *(const float4*)(gw + c * 32 + kq * 4);
    float4 b4 = *(const float4*)(gb + c * 32 + kq * 4);
    #pragma unroll
    for (int i = 0; i < 4; ++i)
      zv[i] = *(const float4*)(zbase + (size_t)(i * 32 + rw) * DIMC + c * 32 + kq * 4);
    // read chunk c-1 B-fragments (this wave's 32 positions)
    {
      const _Float16* Zr = ((c - 1) & 1) ? Zs1 : Zs0;
      #pragma unroll
      for (int ks = 0; ks < 2; ++ks) {
        const int ko = ks * 16 + hq * 8;
        zfh[c - 1][ks] = *(const half8_t*)&Zr[(w * 32 + col) * 72 + ko];
        zfl[c - 1][ks] = *(const half8_t*)&Zr[(w * 32 + col) * 72 + 32 + ko];
      }
    }
    // normalize + split chunk c into the other buffer
    {
      _Float16* Zw = (c & 1) ? Zs1 : Zs0;
      #pragma unroll
      for (int i = 0; i < 4; ++i) {
        int row = i * 32 + rw;
        float zn0 = (zv[i].x - mean) * rstd * w4.x + b4.x;
        float zn1 = (zv[i].y - mean) * rstd * w4.y + b4.y;
        float zn2 = (zv[i].z - mean) * rstd * w4.z + b4.z;
        float zn3 = (zv[i].w - mean) * rstd * w4.w + b4.w;
        half4_t hh, ll;
        { _Float16 h = (_Float16)zn0; hh[0] = h; ll[0] = (_Float16)(zn0 - (float)h); }
        { _Float16 h = (_Float16)zn1; hh[1] = h; ll[1] = (_Float16)(zn1 - (float)h); }
        { _Float16 h = (_Float16)zn2; hh[2] = h; ll[2] = (_Float16)(zn2 - (float)h); }
        { _Float16 h = (_Float16)zn3; hh[3] = h; ll[3] = (_Float16)(zn3 - (float)h); }
        *(half4_t*)&Zw[row * 72 + kq * 4]      = hh;
        *(half4_t*)&Zw[row * 72 + 32 + kq * 4] = ll;
      }
    }
  }
  __syncthreads();
  #pragma unroll
  for (int ks = 0; ks < 2; ++ks) {      // chunk 7 fragments from Zs1
    const int ko = ks * 16 + hq * 8;
    zfh[7][ks] = *(const half8_t*)&Zs1[(w * 32 + col) * 72 + ko];
    zfl[7][ks] = *(const half8_t*)&Zs1[(w * 32 + col) * 72 + 32 + ko];
  }

  // ---------------- phase VQ: 10 code tiles, dbuf GLL, argmin ----------------
  float bv = 3.4e38f; int bi = 0x7fffffff;
  for (int mt = 0; mt < 10; ++mt) {
    const _Float16* Eb = (mt & 1) ? EsA : EsB;
    __syncthreads();                    // drains tile-mt GLL; frees other buf
    if (mt < 9) {                       // prefetch next tile (overlaps MFMAs)
      const char* ec = (const char*)Eimg + (size_t)(mt + 1) * 36864;
      char* eb = (mt & 1) ? (char*)EsB : (char*)EsA;
      #pragma unroll
      for (int i = 0; i < 9; ++i) {
        int off = (w * 9 + i) * 1024 + lane * 16;
        GLL(ec + off, eb + off);
      }
    }
    floatx16 vacc;
    #pragma unroll
    for (int e = 0; e < 16; ++e) vacc[e] = 0.f;
    #pragma unroll
    for (int c = 0; c < 8; ++c)
      #pragma unroll
      for (int ks = 0; ks < 2; ++ks) {
        const int ko = ks * 16 + hq * 8;
        half8_t aeh = *(const half8_t*)&Eb[(c * 32 + col) * 72 + ko];
        half8_t ael = *(const half8_t*)&Eb[(c * 32 + col) * 72 + 32 + ko];
        vacc = MFMA32(aeh, zfh[c][ks], vacc, 0, 0, 0);
        vacc = MFMA32(aeh, zfl[c][ks], vacc, 0, 0, 0);
        vacc = MFMA32(ael, zfh[c][ks], vacc, 0, 0, 0);
      }
    #pragma unroll
    for (int r = 0; r < 16; ++r) {
      int code = mt * 32 + (r & 3) + 8 * (r >> 2) + 4 * hq;
      float d = e2sh[code] - 2.0f * vacc[r];
      if (d < bv || (d == bv && code < bi)) { bv = d; bi = code; }
    }
  }
  {
    float ov = __shfl_xor(bv, 32);
    int   oi = __shfl_xor(bi, 32);
    if (ov < bv || (ov == bv && oi < bi)) { bv = ov; bi = oi; }
  }
  if (hq == 0) idxs[w * 32 + col] = bi;
  __syncthreads();

  // epilogue: out rows = emb[idx] (pure gather, verbatim)
  #pragma unroll
  for (int it = 0; it < 32; ++it) {
    int idx = it * 256 + t;             // 0..8191
    int row = idx >> 6, q4 = (idx & 63) * 4;
    int id = idxs[row];
    float4 e4 = *(const float4*)(emb + (size_t)id * VD + q4);
    *(float4*)(zbase + (size_t)row * DIMC + q4) = e4;
  }
}

extern "C" void kernel_launch(void* const* d_in, const int* in_sizes, int n_in,
                              void* d_out, int out_size, void* d_ws, size_t ws_size,
                              hipStream_t stream) {
  const float* x   = (const float*)d_in[0];
  const float* W   = (const float*)d_in[1];   // (2,256,256)
  const float* gnw = (const float*)d_in[2];   // (512,)
  const float* gnb = (const float*)d_in[3];   // (512,)
  const float* emb = (const float*)d_in[4];   // (320,1,256)
  float* out = (float*)d_out;

  double*   stats = (double*)d_ws;                       // 512 B
  float*    e2f   = (float*)((char*)d_ws + 512);         // 1280 B
  _Float16* Wimg  = (_Float16*)((char*)d_ws + 2048);     // 589824 B
  _Float16* Eimg  = (_Float16*)((char*)d_ws + 591872);   // 368640 B -> 960512 total

  k_prep<<<106, 256, 0, stream>>>(W, emb, Wimg, Eimg, e2f, stats);
  k_proj<<<512, 256, 0, stream>>>(x, Wimg, out, stats);
  k_vq<<<512, 256, 0, stream>>>(out, emb, Eimg, gnw, gnb, stats, e2f);
}